// Round 5
// baseline (230.904 us; speedup 1.0000x reference)
//
#include <hip/hip_runtime.h>
#include <math.h>

// Problem constants (fixed by reference setup_inputs)
constexpr int B = 32;
constexpr int L = 8;
constexpr int P = 1024;
constexpr int S = 1023;          // segments per lane
constexpr float EPS = 1e-8f;

#define INV8PI 0.039788735772973836  // 1/(8*pi)
#define INV2PI 0.15915494309189535   // 1/(2*pi)

typedef float f32x2 __attribute__((ext_vector_type(2)));

// seg = {dlx, dly, midx, midy}, faithful to reference:
// diff = p[i+1]-p[i]; scale = sqrt(s2)/sqrt(s2+eps); dl = diff*scale; mid = avg
__device__ __forceinline__ float4 make_seg(const float2* __restrict__ pts, int i) {
    float2 a = pts[i];
    float2 b = pts[i + 1];
    float dx = b.x - a.x, dy = b.y - a.y;
    float s2 = dx * dx + dy * dy;
    float len = sqrtf(s2);
    float scale = len / sqrtf(s2 + EPS);
    float4 r;
    r.x = dx * scale;
    r.y = dy * scale;
    r.z = 0.5f * (a.x + b.x);
    r.w = 0.5f * (a.y + b.y);
    return r;
}

// grid: (12, 256). blockIdx.y = lane (b*L+l). blockIdx.x: mtype = x>>2 (0=PP,1=GG,2=PG),
// rtile = x&3. Each thread owns one row segment; column segments staged in LDS as
// SoA so pairs (j, j+1) are processed with packed fp32 (v_pk_fma_f32) ops.
__global__ __launch_bounds__(256, 8) void
pair_kernel(const float* __restrict__ pred, const float* __restrict__ gt,
            double* __restrict__ acc) {
    __shared__ float sdlx[1024];     // SoA column tile, 16 KB total
    __shared__ float sdly[1024];
    __shared__ float smx[1024];
    __shared__ float smy[1024];
    __shared__ double wsum[4];

    const int lane  = blockIdx.y;
    const int part  = blockIdx.x;
    const int mtype = part >> 2;     // 0: pred-pred, 1: gt-gt, 2: pred-gt
    const int rtile = part & 3;
    const int tid   = threadIdx.x;

    const float2* rowpts = (const float2*)(mtype == 1 ? gt : pred) + (size_t)lane * P;
    const float2* colpts = (const float2*)(mtype == 0 ? pred : gt) + (size_t)lane * P;

    // stage column segments (stride-1 SoA writes -> conflict-free)
    for (int j = tid; j < S; j += 256) {
        float4 s = make_seg(colpts, j);
        sdlx[j] = s.x; sdly[j] = s.y; smx[j] = s.z; smy[j] = s.w;
    }
    if (tid == 0) {
        // pad index 1023 with zero segment: dot==0 and d2>=1e-30 -> contributes exactly 0
        sdlx[1023] = 0.f; sdly[1023] = 0.f; smx[1023] = 0.f; smy[1023] = 0.f;
    }

    // this thread's row segment
    const int i = rtile * 256 + tid;
    float rx, ry, mz, mw;
    if (i < S) {
        float4 rs = make_seg(rowpts, i);
        rx = rs.x; ry = rs.y; mz = rs.z; mw = rs.w;
    } else {
        rx = 0.f; ry = 0.f; mz = 0.f; mw = 0.f;  // dot=0 -> contributes 0
    }
    __syncthreads();

    // packed row constants (both halves identical)
    const f32x2 rx2 = {rx, rx}, ry2 = {ry, ry}, mz2 = {mz, mz}, mw2 = {mw, mw};
    const f32x2 eps2 = {1e-30f, 1e-30f};

    const f32x2* pdlx = (const f32x2*)sdlx;
    const f32x2* pdly = (const f32x2*)sdly;
    const f32x2* pmx  = (const f32x2*)smx;
    const f32x2* pmy  = (const f32x2*)smy;

    double accd = 0.0;

    // line term: sum |dl| (once per lane per curve; 1/(8pi) matches self blocks)
    if (mtype < 2 && rtile == 0) {
        float lf = 0.0f;
        for (int j = tid; j < S; j += 256) {
            lf += sqrtf(sdlx[j] * sdlx[j] + sdly[j] * sdly[j]);
        }
        accd += (double)lf;
    }

    int jmain;
    if (mtype == 2) {
        jmain = 0;                    // full rectangular, no mask
    } else {
        // diagonal 64-wide chunk: wave-uniform start (i & ~63), per-lane mask j > i
        const int ws = i & ~63;
        const int je = (ws + 64 < S) ? (ws + 64) : S;
        float pf = 0.0f;
        for (int j = ws; j < je; ++j) {
            float rdx = smx[j] - mz;
            float rdy = smy[j] - mw;
            float d2  = fmaf(rdx, rdx, fmaf(rdy, rdy, 1e-30f));
            float dot = fmaf(rx, sdlx[j], ry * sdly[j]);
            float t   = dot * __builtin_amdgcn_rsqf(d2);
            pf += (j > i) ? t : 0.0f;
        }
        accd += (double)pf;
        jmain = ws + 64;              // unmasked (and even) from next chunk on
    }

    // main unmasked pair loop: packed fp32, 2 pairs per iteration.
    // chunked (256 j's) so the float accumulator stays short (precision).
    for (int j0 = jmain; j0 < 1024; j0 += 256) {
        const int je = (j0 + 256 < 1024) ? (j0 + 256) : 1024;
        f32x2 accf = {0.f, 0.f};
#pragma unroll 4
        for (int jp = j0 >> 1; jp < (je >> 1); ++jp) {
            f32x2 cx = pdlx[jp];          // uniform LDS addr -> broadcast b64 reads
            f32x2 cy = pdly[jp];
            f32x2 cmx = pmx[jp];
            f32x2 cmy = pmy[jp];
            f32x2 rdx = cmx - mz2;        // v_pk_add (neg)
            f32x2 rdy = cmy - mw2;
            f32x2 d2  = rdx * rdx + (rdy * rdy + eps2);   // 2x v_pk_fma
            f32x2 dot = rx2 * cx + ry2 * cy;              // pk_mul + pk_fma
            f32x2 rs2;
            rs2.x = __builtin_amdgcn_rsqf(d2.x);
            rs2.y = __builtin_amdgcn_rsqf(d2.y);
            accf += dot * rs2;                            // v_pk_fma
        }
        accd += (double)accf.x + (double)accf.y;
    }

    // wave reduce (64 lanes), then cross-wave via LDS, one double atomic per block
    for (int off = 32; off; off >>= 1) accd += __shfl_down(accd, off, 64);
    if ((tid & 63) == 0) wsum[tid >> 6] = accd;
    __syncthreads();
    if (tid == 0) {
        double tot = wsum[0] + wsum[1] + wsum[2] + wsum[3];
        double coef = (mtype == 2) ? INV2PI : INV8PI;
        // loss = line_p + line_g + sum_PP dot/(8 pi r) + sum_GG dot/(8 pi r) + sum_PG dot/(2 pi r)
        atomicAdd(acc, tot * coef);
    }
}

__global__ void finalize_kernel(const double* __restrict__ acc, float* __restrict__ out) {
    out[0] = (float)(acc[0] / (double)B);
}

extern "C" void kernel_launch(void* const* d_in, const int* in_sizes, int n_in,
                              void* d_out, int out_size, void* d_ws, size_t ws_size,
                              hipStream_t stream) {
    const float* pred = (const float*)d_in[0];
    const float* gt   = (const float*)d_in[1];
    double* acc = (double*)d_ws;

    hipMemsetAsync(d_ws, 0, sizeof(double), stream);

    dim3 grid(12, 256);
    pair_kernel<<<grid, dim3(256), 0, stream>>>(pred, gt, acc);
    finalize_kernel<<<1, 1, 0, stream>>>(acc, (float*)d_out);
}

// Round 6
// 193.678 us; speedup vs baseline: 1.1922x; 1.1922x over previous
//
#include <hip/hip_runtime.h>
#include <math.h>

// Problem constants (fixed by reference setup_inputs)
constexpr int B = 32;
constexpr int P = 1024;
constexpr int S = 1023;          // segments per lane
constexpr float EPS = 1e-8f;

#define INV8PI 0.039788735772973836  // 1/(8*pi)
#define INV2PI 0.15915494309189535   // 1/(2*pi)

typedef float f32x2 __attribute__((ext_vector_type(2)));
typedef float f32x4 __attribute__((ext_vector_type(4)));

// seg = {dlx, dly, midx, midy}, faithful to reference:
// diff = p[i+1]-p[i]; scale = sqrt(s2)/sqrt(s2+eps); dl = diff*scale; mid = avg
__device__ __forceinline__ float4 make_seg(const float2* __restrict__ pts, int i) {
    float2 a = pts[i];
    float2 b = pts[i + 1];
    float dx = b.x - a.x, dy = b.y - a.y;
    float s2 = dx * dx + dy * dy;
    float scale = sqrtf(s2) / sqrtf(s2 + EPS);
    float4 r;
    r.x = dx * scale;
    r.y = dy * scale;
    r.z = 0.5f * (a.x + b.x);
    r.w = 0.5f * (a.y + b.y);
    return r;
}

// grid: (3, 256). blockIdx.y = lane (b*L+l). blockIdx.x = mtype (0 PP, 1 GG, 2 PG).
// Wave v owns rows [256v, 256v+256); lane l owns 4 consecutive rows 256v+4l+k.
// Columns staged in LDS as SoA, read as f32x4 (1 ds_read_b128 per 4 cols per array),
// each read amortized over 4 rows -> LDS instrs/pair cut ~8x vs 1 b128/pair.
__global__ __launch_bounds__(256, 4) void
pair_kernel(const float* __restrict__ pred, const float* __restrict__ gt,
            double* __restrict__ acc) {
    __shared__ float sdlx[1024];     // SoA column tile, 16 KB total
    __shared__ float sdly[1024];
    __shared__ float smx[1024];
    __shared__ float smy[1024];
    __shared__ double wsum[4];

    const int lane  = blockIdx.y;
    const int mtype = blockIdx.x;    // 0: pred-pred, 1: gt-gt, 2: pred-gt
    const int tid   = threadIdx.x;
    const int wv    = tid >> 6;      // wave 0..3
    const int l     = tid & 63;

    const float2* rowpts = (const float2*)(mtype == 1 ? gt : pred) + (size_t)lane * P;
    const float2* colpts = (const float2*)(mtype == 0 ? pred : gt) + (size_t)lane * P;

    // stage column segments (stride-1 SoA writes -> conflict-free)
    for (int j = tid; j < S; j += 256) {
        float4 s = make_seg(colpts, j);
        sdlx[j] = s.x; sdly[j] = s.y; smx[j] = s.z; smy[j] = s.w;
    }
    if (tid == 0) {
        // pad index 1023 with zero segment: dot==0, d2>=1e-30 -> contributes exactly 0
        sdlx[S] = 0.f; sdly[S] = 0.f; smx[S] = 0.f; smy[S] = 0.f;
    }

    // this thread's 4 row segments (packed splats; row >= S is zeroed -> contributes 0)
    const int i0 = 256 * wv + 4 * l;
    f32x2 rx2[4], ry2[4], mx2[4], my2[4];
#pragma unroll
    for (int k = 0; k < 4; ++k) {
        float rx = 0.f, ry = 0.f, mx = 0.f, my = 0.f;
        if (i0 + k < S) {
            float4 r = make_seg(rowpts, i0 + k);
            rx = r.x; ry = r.y; mx = r.z; my = r.w;
        }
        rx2[k] = {rx, rx}; ry2[k] = {ry, ry}; mx2[k] = {mx, mx}; my2[k] = {my, my};
    }
    __syncthreads();

    double accd = 0.0;

    // line term: sum |dl| (once per lane per curve; 1/(8pi) matches self blocks)
    if (mtype < 2) {
        float lf = 0.f;
        for (int j = tid; j < S; j += 256)
            lf += sqrtf(sdlx[j] * sdlx[j] + sdly[j] * sdly[j]);
        accd += (double)lf;
    }

    const f32x4* qx  = (const f32x4*)sdlx;
    const f32x4* qy  = (const f32x4*)sdly;
    const f32x4* qmx = (const f32x4*)smx;
    const f32x4* qmy = (const f32x4*)smy;
    const f32x2 eps2 = {1e-30f, 1e-30f};

    int cstart;
    if (mtype == 2) {
        cstart = 0;                  // full rectangular, no mask
    } else {
        cstart = wv + 1;
        // diagonal superblock: cols [256wv, 256wv+256), per-row mask j > i_k
        f32x2 a[4] = {{0.f,0.f},{0.f,0.f},{0.f,0.f},{0.f,0.f}};
#pragma unroll 2
        for (int q = 64 * wv; q < 64 * wv + 64; ++q) {
            f32x4 x4 = qx[q], y4 = qy[q], u4 = qmx[q], v4 = qmy[q];
            const int j0 = 4 * q;
#pragma unroll
            for (int h = 0; h < 2; ++h) {
                f32x2 cx = h ? (f32x2){x4.z, x4.w} : (f32x2){x4.x, x4.y};
                f32x2 cy = h ? (f32x2){y4.z, y4.w} : (f32x2){y4.x, y4.y};
                f32x2 cu = h ? (f32x2){u4.z, u4.w} : (f32x2){u4.x, u4.y};
                f32x2 cv = h ? (f32x2){v4.z, v4.w} : (f32x2){v4.x, v4.y};
                const int jb = j0 + 2 * h;
#pragma unroll
                for (int k = 0; k < 4; ++k) {
                    f32x2 rdx = cu - mx2[k];
                    f32x2 rdy = cv - my2[k];
                    f32x2 d2  = rdx * rdx + (rdy * rdy + eps2);
                    f32x2 dot = rx2[k] * cx + ry2[k] * cy;
                    f32x2 rs;
                    rs.x = __builtin_amdgcn_rsqf(d2.x);
                    rs.y = __builtin_amdgcn_rsqf(d2.y);
                    f32x2 t = dot * rs;
                    const int ik = i0 + k;
                    t.x = (jb     > ik) ? t.x : 0.f;
                    t.y = (jb + 1 > ik) ? t.y : 0.f;
                    a[k] += t;
                }
            }
        }
        double fl = 0.0;
#pragma unroll
        for (int k = 0; k < 4; ++k) fl += (double)a[k].x + (double)a[k].y;
        accd += fl;
    }

    // unmasked main loop: chunks of 256 cols (64 supers) so fp32 accs stay short
    for (int c = cstart; c < 4; ++c) {
        f32x2 a[4] = {{0.f,0.f},{0.f,0.f},{0.f,0.f},{0.f,0.f}};
#pragma unroll 2
        for (int q = 64 * c; q < 64 * c + 64; ++q) {
            f32x4 x4 = qx[q], y4 = qy[q], u4 = qmx[q], v4 = qmy[q];
#pragma unroll
            for (int h = 0; h < 2; ++h) {
                f32x2 cx = h ? (f32x2){x4.z, x4.w} : (f32x2){x4.x, x4.y};
                f32x2 cy = h ? (f32x2){y4.z, y4.w} : (f32x2){y4.x, y4.y};
                f32x2 cu = h ? (f32x2){u4.z, u4.w} : (f32x2){u4.x, u4.y};
                f32x2 cv = h ? (f32x2){v4.z, v4.w} : (f32x2){v4.x, v4.y};
#pragma unroll
                for (int k = 0; k < 4; ++k) {
                    f32x2 rdx = cu - mx2[k];
                    f32x2 rdy = cv - my2[k];
                    f32x2 d2  = rdx * rdx + (rdy * rdy + eps2);
                    f32x2 dot = rx2[k] * cx + ry2[k] * cy;
                    f32x2 rs;
                    rs.x = __builtin_amdgcn_rsqf(d2.x);
                    rs.y = __builtin_amdgcn_rsqf(d2.y);
                    a[k] += dot * rs;
                }
            }
        }
        double fl = 0.0;
#pragma unroll
        for (int k = 0; k < 4; ++k) fl += (double)a[k].x + (double)a[k].y;
        accd += fl;
    }

    // wave reduce (64 lanes), then cross-wave via LDS, one double atomic per block
    for (int off = 32; off; off >>= 1) accd += __shfl_down(accd, off, 64);
    if ((tid & 63) == 0) wsum[tid >> 6] = accd;
    __syncthreads();
    if (tid == 0) {
        double tot = wsum[0] + wsum[1] + wsum[2] + wsum[3];
        double coef = (mtype == 2) ? INV2PI : INV8PI;
        // loss = line_p + line_g + sum_PP dot/(8 pi r) + sum_GG dot/(8 pi r) + sum_PG dot/(2 pi r)
        atomicAdd(acc, tot * coef);
    }
}

__global__ void finalize_kernel(const double* __restrict__ acc, float* __restrict__ out) {
    out[0] = (float)(acc[0] / (double)B);
}

extern "C" void kernel_launch(void* const* d_in, const int* in_sizes, int n_in,
                              void* d_out, int out_size, void* d_ws, size_t ws_size,
                              hipStream_t stream) {
    const float* pred = (const float*)d_in[0];
    const float* gt   = (const float*)d_in[1];
    double* acc = (double*)d_ws;

    hipMemsetAsync(d_ws, 0, sizeof(double), stream);

    dim3 grid(3, 256);
    pair_kernel<<<grid, dim3(256), 0, stream>>>(pred, gt, acc);
    finalize_kernel<<<1, 1, 0, stream>>>(acc, (float*)d_out);
}

// Round 10
// 188.228 us; speedup vs baseline: 1.2267x; 1.0290x over previous
//
#include <hip/hip_runtime.h>
#include <math.h>

// Problem constants (fixed by reference setup_inputs)
constexpr int B = 32;
constexpr int P = 1024;
constexpr int S = 1023;          // segments per lane
constexpr float EPS = 1e-8f;

#define INV8PI 0.039788735772973836  // 1/(8*pi)
#define INV2PI 0.15915494309189535   // 1/(2*pi)  (= 2*alpha/(4*pi), sign folded)

typedef float f32x4 __attribute__((ext_vector_type(4)));

// 36 balanced work units per lane: (mtype, row-block, col-block), 256x256 each.
// PP upper-tri (10) + GG upper-tri (10) + PG full (16). Diag units masked j>i.
__device__ const unsigned char UMT[36] = {
    0,0,0,0,0,0,0,0,0,0,
    1,1,1,1,1,1,1,1,1,1,
    2,2,2,2,2,2,2,2,2,2,2,2,2,2,2,2};
__device__ const unsigned char URB[36] = {
    0,0,0,0,1,1,1,2,2,3,
    0,0,0,0,1,1,1,2,2,3,
    0,0,0,0,1,1,1,1,2,2,2,2,3,3,3,3};
__device__ const unsigned char UCB[36] = {
    0,1,2,3,1,2,3,2,3,3,
    0,1,2,3,1,2,3,2,3,3,
    0,1,2,3,0,1,2,3,0,1,2,3,0,1,2,3};

// seg = {dlx, dly, midx, midy}, faithful to reference:
// diff = p[i+1]-p[i]; scale = sqrt(s2)/sqrt(s2+eps); dl = diff*scale; mid = avg
__device__ __forceinline__ float4 make_seg(const float2* __restrict__ pts, int i) {
    float2 a = pts[i];
    float2 b = pts[i + 1];
    float dx = b.x - a.x, dy = b.y - a.y;
    float s2 = dx * dx + dy * dy;
    float scale = sqrtf(s2) / sqrtf(s2 + EPS);
    float4 r;
    r.x = dx * scale;
    r.y = dy * scale;
    r.z = 0.5f * (a.x + b.x);
    r.w = 0.5f * (a.y + b.y);
    return r;
}

// grid: (3, 256). blockIdx.y = lane. blockIdx.x = ublk (unit group 0..2).
// Block stages BOTH curves' segments (SoA, 32 KB). Wave wv processes units
// {12*ublk + wv + 4*t, t=0..2} -> every wave in the grid does identical work.
__global__ __launch_bounds__(256, 4) void
pair_kernel(const float* __restrict__ pred, const float* __restrict__ gt,
            double* __restrict__ acc) {
    __shared__ float sA[2][4][1024];   // [pred/gt][dlx,dly,mx,my][seg] = 32 KB
    __shared__ double wsum[8];         // 4 waves x {self, int}

    const int lane = blockIdx.y;
    const int ublk = blockIdx.x;       // 0..2
    const int tid  = threadIdx.x;
    const int wv   = tid >> 6;
    const int l    = tid & 63;

    const float2* pp = (const float2*)pred + (size_t)lane * P;
    const float2* pg = (const float2*)gt   + (size_t)lane * P;

    // stage both curves' segments (stride-1 SoA writes, conflict-free)
    for (int j = tid; j < S; j += 256) {
        float4 s = make_seg(pp, j);
        sA[0][0][j] = s.x; sA[0][1][j] = s.y; sA[0][2][j] = s.z; sA[0][3][j] = s.w;
        float4 t = make_seg(pg, j);
        sA[1][0][j] = t.x; sA[1][1][j] = t.y; sA[1][2][j] = t.z; sA[1][3][j] = t.w;
    }
    if (tid == 0) {
        // zero pad seg 1023: dot==0, d2>=1e-30 -> contributes exactly 0
        sA[0][0][S] = 0.f; sA[0][1][S] = 0.f; sA[0][2][S] = 0.f; sA[0][3][S] = 0.f;
        sA[1][0][S] = 0.f; sA[1][1][S] = 0.f; sA[1][2][S] = 0.f; sA[1][3][S] = 0.f;
    }
    __syncthreads();

    double acc_self = 0.0, acc_int = 0.0;

    // line terms: once per lane globally -> only ublk==0 blocks (tiny, 16 sqrt/thread)
    if (ublk == 0) {
        float lf = 0.f;
        for (int j = tid; j < S; j += 256) {
            lf += sqrtf(sA[0][0][j] * sA[0][0][j] + sA[0][1][j] * sA[0][1][j]);
            lf += sqrtf(sA[1][0][j] * sA[1][0][j] + sA[1][1][j] * sA[1][1][j]);
        }
        acc_self += (double)lf;
    }

    for (int t = 0; t < 3; ++t) {
        const int u  = 12 * ublk + wv + 4 * t;
        const int mt = UMT[u], rb = URB[u], cb = UCB[u];
        const int rm = (mt == 1) ? 1 : 0;   // row matrix: GG->gt else pred
        const int cm = (mt == 0) ? 0 : 1;   // col matrix: PP->pred else gt

        // 4 row segments (rows rb*256 + 4l + k) via one b128 per array
        const int rq = rb * 64 + l;
        f32x4 rx4 = ((const f32x4*)sA[rm][0])[rq];
        f32x4 ry4 = ((const f32x4*)sA[rm][1])[rq];
        f32x4 ru4 = ((const f32x4*)sA[rm][2])[rq];
        f32x4 rv4 = ((const f32x4*)sA[rm][3])[rq];
        const float rx[4] = {rx4.x, rx4.y, rx4.z, rx4.w};
        const float ry[4] = {ry4.x, ry4.y, ry4.z, ry4.w};
        const float ru[4] = {ru4.x, ru4.y, ru4.z, ru4.w};
        const float rv[4] = {rv4.x, rv4.y, rv4.z, rv4.w};

        const f32x4* qx = (const f32x4*)sA[cm][0];
        const f32x4* qy = (const f32x4*)sA[cm][1];
        const f32x4* qu = (const f32x4*)sA[cm][2];
        const f32x4* qv = (const f32x4*)sA[cm][3];

        f32x4 a[4] = {{0,0,0,0},{0,0,0,0},{0,0,0,0},{0,0,0,0}};
        const int q0 = cb * 64;
        const int i0 = rb * 256 + 4 * l;
        const bool masked = (mt < 2) && (rb == cb);

        if (!masked) {
#pragma unroll 2
            for (int q = q0; q < q0 + 64; ++q) {
                f32x4 cx = qx[q], cy = qy[q], cu = qu[q], cv = qv[q];
#pragma unroll
                for (int k = 0; k < 4; ++k) {
                    f32x4 rdx = cu - ru[k];
                    f32x4 rdy = cv - rv[k];
                    f32x4 d2  = rdx * rdx + (rdy * rdy + (f32x4)1e-30f);
                    f32x4 dot = rx[k] * cx + ry[k] * cy;
                    f32x4 rs;
                    rs.x = __builtin_amdgcn_rsqf(d2.x);
                    rs.y = __builtin_amdgcn_rsqf(d2.y);
                    rs.z = __builtin_amdgcn_rsqf(d2.z);
                    rs.w = __builtin_amdgcn_rsqf(d2.w);
                    a[k] += dot * rs;
                }
            }
        } else {
#pragma unroll 2
            for (int q = q0; q < q0 + 64; ++q) {
                f32x4 cx = qx[q], cy = qy[q], cu = qu[q], cv = qv[q];
                const int jb = 4 * q;
#pragma unroll
                for (int k = 0; k < 4; ++k) {
                    f32x4 rdx = cu - ru[k];
                    f32x4 rdy = cv - rv[k];
                    f32x4 d2  = rdx * rdx + (rdy * rdy + (f32x4)1e-30f);
                    f32x4 dot = rx[k] * cx + ry[k] * cy;
                    f32x4 rs;
                    rs.x = __builtin_amdgcn_rsqf(d2.x);
                    rs.y = __builtin_amdgcn_rsqf(d2.y);
                    rs.z = __builtin_amdgcn_rsqf(d2.z);
                    rs.w = __builtin_amdgcn_rsqf(d2.w);
                    f32x4 tv = dot * rs;
                    const int ik = i0 + k;
                    tv.x = (jb + 0 > ik) ? tv.x : 0.f;
                    tv.y = (jb + 1 > ik) ? tv.y : 0.f;
                    tv.z = (jb + 2 > ik) ? tv.z : 0.f;
                    tv.w = (jb + 3 > ik) ? tv.w : 0.f;
                    a[k] += tv;
                }
            }
        }

        // flush unit accumulators (each component summed <=64 fp32 terms) to double
        double su = 0.0;
#pragma unroll
        for (int k = 0; k < 4; ++k)
            su += (double)a[k].x + (double)a[k].y + (double)a[k].z + (double)a[k].w;
        if (mt == 2) acc_int += su; else acc_self += su;
    }

    // wave reduce, then cross-wave via LDS, one double atomic per block
    for (int off = 32; off; off >>= 1) {
        acc_self += __shfl_down(acc_self, off, 64);
        acc_int  += __shfl_down(acc_int,  off, 64);
    }
    if (l == 0) { wsum[wv] = acc_self; wsum[4 + wv] = acc_int; }
    __syncthreads();
    if (tid == 0) {
        double ts = wsum[0] + wsum[1] + wsum[2] + wsum[3];
        double ti = wsum[4] + wsum[5] + wsum[6] + wsum[7];
        // loss = lines + sum_PP dot/(8 pi r) + sum_GG dot/(8 pi r) + sum_PG dot/(2 pi r)
        atomicAdd(acc, ts * INV8PI + ti * INV2PI);
    }
}

__global__ void finalize_kernel(const double* __restrict__ acc, float* __restrict__ out) {
    out[0] = (float)(acc[0] / (double)B);
}

extern "C" void kernel_launch(void* const* d_in, const int* in_sizes, int n_in,
                              void* d_out, int out_size, void* d_ws, size_t ws_size,
                              hipStream_t stream) {
    const float* pred = (const float*)d_in[0];
    const float* gt   = (const float*)d_in[1];
    double* acc = (double*)d_ws;

    hipMemsetAsync(d_ws, 0, sizeof(double), stream);

    dim3 grid(3, 256);
    pair_kernel<<<grid, dim3(256), 0, stream>>>(pred, gt, acc);
    finalize_kernel<<<1, 1, 0, stream>>>(acc, (float*)d_out);
}